// Round 2
// baseline (462.294 us; speedup 1.0000x reference)
//
#include <hip/hip_runtime.h>
#include <stdint.h>

#define E_  8
#define H_  768
#define I_  1152
#define T_  4096
#define F2_ (2*I_)   // 2304

typedef unsigned short u16;
typedef __attribute__((ext_vector_type(8))) __bf16 bf16x8;
typedef __attribute__((ext_vector_type(4))) float floatx4;

typedef const void __attribute__((address_space(1))) as1_void;
typedef void __attribute__((address_space(3))) as3_void;

__device__ __forceinline__ void gld16(void* lds, const void* g) {
  __builtin_amdgcn_global_load_lds((as1_void*)g, (as3_void*)lds, 16, 0, 0);
}

__device__ __forceinline__ u16 f2bf(float f) {
  union { float f; unsigned int i; } v; v.f = f;
  unsigned int r = v.i + 0x7FFF + ((v.i >> 16) & 1);  // round-to-nearest-even
  return (u16)(r >> 16);
}

// ---------------- fp32 -> bf16 convert (N multiple of 1024) ----------------
__global__ void convert_f2b(const float* __restrict__ src, u16* __restrict__ dst) {
  int i = (blockIdx.x * 256 + threadIdx.x) * 4;
  float4 v = *(const float4*)(src + i);
  ushort4 u;
  u.x = f2bf(v.x); u.y = f2bf(v.y); u.z = f2bf(v.z); u.w = f2bf(v.w);
  *(ushort4*)(dst + i) = u;
}

// ------------- transpose + convert: src fp32 (R x C) -> dst bf16 (C x R), per z ----------
__global__ void transpose_f2b(const float* __restrict__ src, u16* __restrict__ dst,
                              int R, int C) {
  __shared__ u16 tile[64][65];
  const float* s = src + (long)blockIdx.z * R * C;
  u16*         d = dst + (long)blockIdx.z * R * C;
  int r0 = blockIdx.y * 64, c0 = blockIdx.x * 64;
  int tx = threadIdx.x, ty = threadIdx.y;   // (64, 8)
  #pragma unroll
  for (int k = 0; k < 64; k += 8)
    tile[ty + k][tx] = f2bf(s[(long)(r0 + ty + k) * C + (c0 + tx)]);
  __syncthreads();
  #pragma unroll
  for (int k = 0; k < 64; k += 8)
    d[(long)(c0 + ty + k) * R + (r0 + tx)] = tile[tx][ty + k];
}

// ---------------- gating: one wave per token (fp32 inputs) ----------------
__global__ void gate_kernel(const float* __restrict__ x, const float* __restrict__ gw,
                            const float* __restrict__ bias,
                            int* __restrict__ top2e, float* __restrict__ top2w,
                            int* __restrict__ count) {
  int t    = blockIdx.x * 4 + (threadIdx.x >> 6);
  int lane = threadIdx.x & 63;
  float acc[E_];
  #pragma unroll
  for (int e = 0; e < E_; e++) acc[e] = 0.f;
  for (int k = lane; k < H_; k += 64) {
    float xv = x[(long)t * H_ + k];
    #pragma unroll
    for (int e = 0; e < E_; e++) acc[e] += xv * gw[e * H_ + k];
  }
  #pragma unroll
  for (int e = 0; e < E_; e++) {
    #pragma unroll
    for (int s = 32; s > 0; s >>= 1) acc[e] += __shfl_xor(acc[e], s);
  }
  if (lane == 0) {
    float logits[E_], sel[E_];
    #pragma unroll
    for (int e = 0; e < E_; e++) {
      logits[e] = 1.f / (1.f + expf(-acc[e]));
      sel[e]    = logits[e] + bias[e];
    }
    int i0 = 0;
    #pragma unroll
    for (int e = 1; e < E_; e++) if (sel[e] > sel[i0]) i0 = e;
    int i1 = (i0 == 0) ? 1 : 0;
    #pragma unroll
    for (int e = 0; e < E_; e++) if (e != i0 && sel[e] > sel[i1]) i1 = e;
    float w0 = logits[i0], w1 = logits[i1], s = w0 + w1;
    top2e[t * 2 + 0] = i0;  top2w[t * 2 + 0] = w0 / s;
    top2e[t * 2 + 1] = i1;  top2w[t * 2 + 1] = w1 / s;
    atomicAdd(&count[i0], 1);
    atomicAdd(&count[i1], 1);
  }
}

__global__ void offsets_kernel(const int* __restrict__ count, int* __restrict__ offs,
                               int* __restrict__ curs) {
  if (threadIdx.x == 0) {
    int s = 0;
    for (int e = 0; e < E_; e++) { offs[e] = s; s += count[e]; curs[e] = 0; }
  }
}

__global__ void scatter_kernel(const int* __restrict__ top2e, const float* __restrict__ top2w,
                               const int* __restrict__ offs, int* __restrict__ curs,
                               int* __restrict__ list, float* __restrict__ wlist) {
  int t = blockIdx.x * 256 + threadIdx.x;
  #pragma unroll
  for (int s = 0; s < 2; s++) {
    int e = top2e[t * 2 + s];
    int j = atomicAdd(&curs[e], 1);
    int g = offs[e] + j;
    list[g]  = t;
    wlist[g] = top2w[t * 2 + s];
  }
}

// ---------------- GEMM1 (+fused SiLU epilogue): act = f(A @ B^T) ----------------
// A: xb (T,H) bf16. B: (2I,H) bf16 row-major (B^T layout). Tile: 128 rows x (64+64) cols.
// EXPERT: gather rows via list, silu(second half)*first*w. else: silu(first)*second.
template<bool EXPERT>
__global__ __launch_bounds__(256, 2)
void gemm_act(const u16* __restrict__ A, const u16* __restrict__ Bbase, long Bstride,
              u16* __restrict__ act, const int* __restrict__ list,
              const float* __restrict__ wlist, const int* __restrict__ counts,
              const int* __restrict__ offsets) {
  __shared__ __align__(16) u16 As[128 * 32];
  __shared__ __align__(16) u16 Bs[2][64 * 32];

  int tid  = threadIdx.x;
  int lane = tid & 63, wv = tid >> 6;
  int wr   = wv >> 1, wc = wv & 1;
  int half = lane & 15, quad = lane >> 4;

  int cnt, off;
  const u16* B = Bbase;
  if (EXPERT) {
    int e = blockIdx.z;
    cnt = counts[e]; off = offsets[e];
    B += (long)e * Bstride;
  } else { cnt = T_; off = 0; }
  int row0 = blockIdx.y * 128;
  if (row0 >= cnt) return;
  int n0 = blockIdx.x * 64;

  int kc  = (tid & 3) * 8;
  int jl0 = row0 + (tid >> 2);
  int jl1 = jl0 + 64;
  int rr0 = min(jl0, cnt - 1), rr1 = min(jl1, cnt - 1);
  int t0  = EXPERT ? list[off + rr0] : rr0;
  int t1  = EXPERT ? list[off + rr1] : rr1;
  const u16* ap0 = A + (long)t0 * H_ + kc;
  const u16* ap1 = A + (long)t1 * H_ + kc;
  int nloc = tid >> 2;
  const u16* bp0 = B + (long)(n0 + nloc) * H_ + kc;
  const u16* bp1 = B + (long)(I_ + n0 + nloc) * H_ + kc;
  u16* asd0 = As + tid * 8;
  u16* asd1 = As + (tid + 256) * 8;
  u16* bsd0 = Bs[0] + tid * 8;
  u16* bsd1 = Bs[1] + tid * 8;

  floatx4 acc[2][4][2];
  #pragma unroll
  for (int p = 0; p < 2; p++)
    #pragma unroll
    for (int i = 0; i < 4; i++)
      #pragma unroll
      for (int j = 0; j < 2; j++) acc[p][i][j] = (floatx4)0.f;

  for (int k0 = 0; k0 < H_; k0 += 32) {
    if (k0) __syncthreads();
    gld16(asd0, ap0 + k0);
    gld16(asd1, ap1 + k0);
    gld16(bsd0, bp0 + k0);
    gld16(bsd1, bp1 + k0);
    __syncthreads();
    bf16x8 a[4], bq[2][2];
    #pragma unroll
    for (int i = 0; i < 4; i++)
      a[i] = *(const bf16x8*)(As + (wr * 64 + i * 16 + half) * 32 + quad * 8);
    #pragma unroll
    for (int p = 0; p < 2; p++)
      #pragma unroll
      for (int j = 0; j < 2; j++)
        bq[p][j] = *(const bf16x8*)(Bs[p] + (wc * 32 + j * 16 + half) * 32 + quad * 8);
    #pragma unroll
    for (int i = 0; i < 4; i++)
      #pragma unroll
      for (int p = 0; p < 2; p++)
        #pragma unroll
        for (int j = 0; j < 2; j++)
          acc[p][i][j] = __builtin_amdgcn_mfma_f32_16x16x32_bf16(a[i], bq[p][j], acc[p][i][j], 0, 0, 0);
  }

  #pragma unroll
  for (int i = 0; i < 4; i++) {
    #pragma unroll
    for (int r = 0; r < 4; r++) {
      int g = row0 + wr * 64 + i * 16 + quad * 4 + r;
      if (g < cnt) {
        float w = EXPERT ? wlist[off + g] : 1.f;
        #pragma unroll
        for (int j = 0; j < 2; j++) {
          float va = acc[0][i][j][r];   // first-half col (proj / s_in)
          float vb = acc[1][i][j][r];   // second-half col (gate)
          float z  = EXPERT ? vb : va;  // expert: silu(gate); shared: silu(s_in)
          float o  = EXPERT ? va : vb;
          float sg = z / (1.f + expf(-z));
          float v  = sg * o * w;
          int col  = n0 + wc * 32 + j * 16 + half;
          act[(long)(off + g) * I_ + col] = f2bf(v);
        }
      }
    }
  }
}

// ---------------- GEMM2: out(+)= act @ B^T  (fp32 output) ----------------
// A: act rows (lda=I) bf16. B: (H,I) bf16 row-major. Block tile 128x128.
template<bool EXPERT>
__global__ __launch_bounds__(256, 2)
void gemm_out_k(const u16* __restrict__ A, const u16* __restrict__ Bbase, long Bstride,
                float* __restrict__ out, const int* __restrict__ list,
                const int* __restrict__ counts, const int* __restrict__ offsets) {
  __shared__ __align__(16) u16 As[128 * 32];
  __shared__ __align__(16) u16 Bs[128 * 32];

  int tid  = threadIdx.x;
  int lane = tid & 63, wv = tid >> 6;
  int wr   = wv >> 1, wc = wv & 1;
  int half = lane & 15, quad = lane >> 4;

  int cnt, off;
  const u16* B = Bbase;
  if (EXPERT) {
    int e = blockIdx.z;
    cnt = counts[e]; off = offsets[e];
    B += (long)e * Bstride;
  } else { cnt = T_; off = 0; }
  int row0 = blockIdx.y * 128;
  if (row0 >= cnt) return;
  int n0 = blockIdx.x * 128;

  int kc  = (tid & 3) * 8;
  int jl0 = row0 + (tid >> 2);
  int jl1 = jl0 + 64;
  long ar0 = off + min(jl0, cnt - 1);
  long ar1 = off + min(jl1, cnt - 1);
  const u16* ap0 = A + ar0 * I_ + kc;
  const u16* ap1 = A + ar1 * I_ + kc;
  int nl0 = n0 + (tid >> 2);
  const u16* bp0 = B + (long)nl0 * I_ + kc;
  const u16* bp1 = B + (long)(nl0 + 64) * I_ + kc;
  u16* asd0 = As + tid * 8;
  u16* asd1 = As + (tid + 256) * 8;
  u16* bsd0 = Bs + tid * 8;
  u16* bsd1 = Bs + (tid + 256) * 8;

  floatx4 acc[4][4];
  #pragma unroll
  for (int i = 0; i < 4; i++)
    #pragma unroll
    for (int j = 0; j < 4; j++) acc[i][j] = (floatx4)0.f;

  for (int k0 = 0; k0 < I_; k0 += 32) {
    if (k0) __syncthreads();
    gld16(asd0, ap0 + k0);
    gld16(asd1, ap1 + k0);
    gld16(bsd0, bp0 + k0);
    gld16(bsd1, bp1 + k0);
    __syncthreads();
    bf16x8 a[4], b[4];
    #pragma unroll
    for (int i = 0; i < 4; i++)
      a[i] = *(const bf16x8*)(As + (wr * 64 + i * 16 + half) * 32 + quad * 8);
    #pragma unroll
    for (int j = 0; j < 4; j++)
      b[j] = *(const bf16x8*)(Bs + (wc * 64 + j * 16 + half) * 32 + quad * 8);
    #pragma unroll
    for (int i = 0; i < 4; i++)
      #pragma unroll
      for (int j = 0; j < 4; j++)
        acc[i][j] = __builtin_amdgcn_mfma_f32_16x16x32_bf16(a[i], b[j], acc[i][j], 0, 0, 0);
  }

  #pragma unroll
  for (int i = 0; i < 4; i++) {
    #pragma unroll
    for (int r = 0; r < 4; r++) {
      int g = row0 + wr * 64 + i * 16 + quad * 4 + r;
      if (g < cnt) {
        int t = EXPERT ? list[off + g] : g;
        float* orow = out + (long)t * H_;
        #pragma unroll
        for (int j = 0; j < 4; j++) {
          int col = n0 + wc * 64 + j * 16 + half;
          float v = acc[i][j][r];
          if (EXPERT) atomicAdd(orow + col, v);
          else        orow[col] = v;
        }
      }
    }
  }
}

extern "C" void kernel_launch(void* const* d_in, const int* in_sizes, int n_in,
                              void* d_out, int out_size, void* d_ws, size_t ws_size,
                              hipStream_t stream) {
  const float* x      = (const float*)d_in[0];
  const float* gate_w = (const float*)d_in[1];
  const float* bias   = (const float*)d_in[2];
  const float* Wi     = (const float*)d_in[3];
  const float* Wo     = (const float*)d_in[4];
  const float* sWi    = (const float*)d_in[5];
  const float* sWo    = (const float*)d_in[6];
  float* out          = (float*)d_out;

  char* ws = (char*)d_ws;
  size_t o = 0;
  auto alloc = [&](size_t bytes) -> void* {
    o = (o + 255) & ~(size_t)255;
    void* p = ws + o;
    o += bytes;
    return p;
  };
  u16*   xb    = (u16*)  alloc((size_t)T_ * H_ * 2);
  u16*   sWib  = (u16*)  alloc((size_t)F2_ * H_ * 2);
  u16*   sWob  = (u16*)  alloc((size_t)H_ * I_ * 2);
  u16*   WiT   = (u16*)  alloc((size_t)E_ * F2_ * H_ * 2);
  u16*   WoT   = (u16*)  alloc((size_t)E_ * H_ * I_ * 2);
  u16*   shact = (u16*)  alloc((size_t)T_ * I_ * 2);
  u16*   ebuf  = (u16*)  alloc((size_t)2 * T_ * I_ * 2);
  int*   top2e = (int*)  alloc((size_t)T_ * 2 * 4);
  float* top2w = (float*)alloc((size_t)T_ * 2 * 4);
  int*   count = (int*)  alloc(E_ * 4);
  int*   offs  = (int*)  alloc(E_ * 4);
  int*   curs  = (int*)  alloc(E_ * 4);
  int*   list  = (int*)  alloc((size_t)2 * T_ * 4);
  float* wlist = (float*)alloc((size_t)2 * T_ * 4);

  hipMemsetAsync(count, 0, E_ * 4, stream);

  // fp32 -> bf16 conversions
  convert_f2b<<<(T_ * H_) / 1024, 256, 0, stream>>>(x, xb);
  convert_f2b<<<(F2_ * H_) / 1024, 256, 0, stream>>>(sWi, sWib);
  convert_f2b<<<(H_ * I_) / 1024, 256, 0, stream>>>(sWo, sWob);
  // weight transposes (+convert) into B^T-friendly layout
  transpose_f2b<<<dim3(F2_ / 64, H_ / 64, E_), dim3(64, 8), 0, stream>>>(Wi, WiT, H_, F2_);
  transpose_f2b<<<dim3(H_ / 64, I_ / 64, E_), dim3(64, 8), 0, stream>>>(Wo, WoT, I_, H_);

  // routing (fp32)
  gate_kernel<<<T_ / 4, 256, 0, stream>>>(x, gate_w, bias, top2e, top2w, count);
  offsets_kernel<<<1, 64, 0, stream>>>(count, offs, curs);
  scatter_kernel<<<T_ / 256, 256, 0, stream>>>(top2e, top2w, offs, curs, list, wlist);

  // shared branch (writes every element of out with plain stores)
  gemm_act<false><<<dim3(I_ / 64, T_ / 128, 1), 256, 0, stream>>>(
      xb, sWib, 0, shact, nullptr, nullptr, nullptr, nullptr);
  gemm_out_k<false><<<dim3(H_ / 128, T_ / 128, 1), 256, 0, stream>>>(
      shact, sWob, 0, out, nullptr, nullptr, nullptr);

  // expert branch (sparse, gathered; atomicAdd into out)
  gemm_act<true><<<dim3(I_ / 64, T_ / 128, E_), 256, 0, stream>>>(
      xb, WiT, (long)F2_ * H_, ebuf, list, wlist, count, offs);
  gemm_out_k<true><<<dim3(H_ / 128, T_ / 128, E_), 256, 0, stream>>>(
      ebuf, WoT, (long)H_ * I_, out, list, count, offs);
}

// Round 3
// 381.022 us; speedup vs baseline: 1.2133x; 1.2133x over previous
//
#include <hip/hip_runtime.h>
#include <stdint.h>

#define E_  8
#define H_  768
#define I_  1152
#define T_  4096
#define F2_ (2*I_)   // 2304

typedef unsigned short u16;
typedef __attribute__((ext_vector_type(8))) __bf16 bf16x8;
typedef __attribute__((ext_vector_type(4))) float floatx4;

typedef const void __attribute__((address_space(1))) as1_void;
typedef void __attribute__((address_space(3))) as3_void;

__device__ __forceinline__ void gld16(void* lds, const void* g) {
  __builtin_amdgcn_global_load_lds((as1_void*)g, (as3_void*)lds, 16, 0, 0);
}

__device__ __forceinline__ u16 f2bf(float f) {
  union { float f; unsigned int i; } v; v.f = f;
  unsigned int r = v.i + 0x7FFF + ((v.i >> 16) & 1);  // round-to-nearest-even
  return (u16)(r >> 16);
}

// ---------------- fp32 -> bf16 convert (N multiple of 1024) ----------------
__global__ void convert_f2b(const float* __restrict__ src, u16* __restrict__ dst) {
  int i = (blockIdx.x * 256 + threadIdx.x) * 4;
  float4 v = *(const float4*)(src + i);
  ushort4 u;
  u.x = f2bf(v.x); u.y = f2bf(v.y); u.z = f2bf(v.z); u.w = f2bf(v.w);
  *(ushort4*)(dst + i) = u;
}

// ------------- transpose + convert: src fp32 (R x C) -> dst bf16 (C x R), per z ----------
__global__ void transpose_f2b(const float* __restrict__ src, u16* __restrict__ dst,
                              int R, int C) {
  __shared__ u16 tile[64][65];
  const float* s = src + (long)blockIdx.z * R * C;
  u16*         d = dst + (long)blockIdx.z * R * C;
  int r0 = blockIdx.y * 64, c0 = blockIdx.x * 64;
  int tx = threadIdx.x, ty = threadIdx.y;   // (64, 8)
  #pragma unroll
  for (int k = 0; k < 64; k += 8)
    tile[ty + k][tx] = f2bf(s[(long)(r0 + ty + k) * C + (c0 + tx)]);
  __syncthreads();
  #pragma unroll
  for (int k = 0; k < 64; k += 8)
    d[(long)(c0 + ty + k) * R + (r0 + tx)] = tile[tx][ty + k];
}

// ---------------- gating: one wave per token (fp32 inputs), NO atomics ----------------
// Also fuses x fp32->bf16 conversion (each x element is read exactly once here).
__global__ void gate_kernel(const float* __restrict__ x, const float* __restrict__ gw,
                            const float* __restrict__ bias,
                            int* __restrict__ top2e, float* __restrict__ top2w,
                            u16* __restrict__ xb) {
  int t    = blockIdx.x * 4 + (threadIdx.x >> 6);
  int lane = threadIdx.x & 63;
  float acc[E_];
  #pragma unroll
  for (int e = 0; e < E_; e++) acc[e] = 0.f;
  #pragma unroll
  for (int k = lane; k < H_; k += 64) {
    float xv = x[(long)t * H_ + k];
    xb[(long)t * H_ + k] = f2bf(xv);
    #pragma unroll
    for (int e = 0; e < E_; e++) acc[e] += xv * gw[e * H_ + k];
  }
  #pragma unroll
  for (int e = 0; e < E_; e++) {
    #pragma unroll
    for (int s = 32; s > 0; s >>= 1) acc[e] += __shfl_xor(acc[e], s);
  }
  if (lane == 0) {
    float logits[E_], sel[E_];
    #pragma unroll
    for (int e = 0; e < E_; e++) {
      logits[e] = 1.f / (1.f + expf(-acc[e]));
      sel[e]    = logits[e] + bias[e];
    }
    int i0 = 0;
    #pragma unroll
    for (int e = 1; e < E_; e++) if (sel[e] > sel[i0]) i0 = e;
    int i1 = (i0 == 0) ? 1 : 0;
    #pragma unroll
    for (int e = 0; e < E_; e++) if (e != i0 && sel[e] > sel[i1]) i1 = e;
    float w0 = logits[i0], w1 = logits[i1], s = w0 + w1;
    top2e[t * 2 + 0] = i0;  top2w[t * 2 + 0] = w0 / s;
    top2e[t * 2 + 1] = i1;  top2w[t * 2 + 1] = w1 / s;
  }
}

// ---------------- build per-expert token lists: single block, zero atomics ----------------
// Wave e owns expert e. Pass 1: ballot-count. Scan by thread 0. Pass 2: stable
// ballot-prefix scatter. Deterministic.
__global__ void build_lists(const int* __restrict__ top2e, const float* __restrict__ top2w,
                            int* __restrict__ counts, int* __restrict__ offs,
                            int* __restrict__ list, float* __restrict__ wlist) {
  __shared__ int lds_cnt[E_];
  __shared__ int lds_off[E_];
  int wv = threadIdx.x >> 6, lane = threadIdx.x & 63;   // 512 threads = 8 waves

  int c = 0;
  for (int s = lane; s < 2 * T_; s += 64)
    if (top2e[s] == wv) c++;
  #pragma unroll
  for (int s = 32; s > 0; s >>= 1) c += __shfl_xor(c, s);
  if (lane == 0) lds_cnt[wv] = c;
  __syncthreads();
  if (threadIdx.x == 0) {
    int s = 0;
    #pragma unroll
    for (int e = 0; e < E_; e++) {
      lds_off[e] = s;
      counts[e]  = lds_cnt[e];
      offs[e]    = s;
      s += lds_cnt[e];
    }
  }
  __syncthreads();

  int base = lds_off[wv];
  unsigned long long lt = (lane == 63) ? ~0ull >> 1 : ((1ull << lane) - 1);
  for (int s0 = 0; s0 < 2 * T_; s0 += 64) {
    int s = s0 + lane;
    bool m = (top2e[s] == wv);
    unsigned long long mask = __ballot(m);
    if (m) {
      int pos = base + __popcll(mask & lt);
      list[pos]  = s >> 1;        // token index
      wlist[pos] = top2w[s];
    }
    base += __popcll(mask);
  }
}

// ---------------- GEMM1 (+fused SiLU epilogue): act = f(A @ B^T) ----------------
// A: xb (T,H) bf16. B: (2I,H) bf16 row-major (B^T layout). Tile: 128 rows x (64+64) cols.
// EXPERT: gather rows via list, silu(second half)*first*w. else: silu(first)*second.
template<bool EXPERT>
__global__ __launch_bounds__(256, 2)
void gemm_act(const u16* __restrict__ A, const u16* __restrict__ Bbase, long Bstride,
              u16* __restrict__ act, const int* __restrict__ list,
              const float* __restrict__ wlist, const int* __restrict__ counts,
              const int* __restrict__ offsets) {
  __shared__ __align__(16) u16 As[128 * 32];
  __shared__ __align__(16) u16 Bs[2][64 * 32];

  int tid  = threadIdx.x;
  int lane = tid & 63, wv = tid >> 6;
  int wr   = wv >> 1, wc = wv & 1;
  int half = lane & 15, quad = lane >> 4;

  int cnt, off;
  const u16* B = Bbase;
  if (EXPERT) {
    int e = blockIdx.z;
    cnt = counts[e]; off = offsets[e];
    B += (long)e * Bstride;
  } else { cnt = T_; off = 0; }
  int row0 = blockIdx.y * 128;
  if (row0 >= cnt) return;
  int n0 = blockIdx.x * 64;

  int kc  = (tid & 3) * 8;
  int jl0 = row0 + (tid >> 2);
  int jl1 = jl0 + 64;
  int rr0 = min(jl0, cnt - 1), rr1 = min(jl1, cnt - 1);
  int t0  = EXPERT ? list[off + rr0] : rr0;
  int t1  = EXPERT ? list[off + rr1] : rr1;
  const u16* ap0 = A + (long)t0 * H_ + kc;
  const u16* ap1 = A + (long)t1 * H_ + kc;
  int nloc = tid >> 2;
  const u16* bp0 = B + (long)(n0 + nloc) * H_ + kc;
  const u16* bp1 = B + (long)(I_ + n0 + nloc) * H_ + kc;
  u16* asd0 = As + tid * 8;
  u16* asd1 = As + (tid + 256) * 8;
  u16* bsd0 = Bs[0] + tid * 8;
  u16* bsd1 = Bs[1] + tid * 8;

  floatx4 acc[2][4][2];
  #pragma unroll
  for (int p = 0; p < 2; p++)
    #pragma unroll
    for (int i = 0; i < 4; i++)
      #pragma unroll
      for (int j = 0; j < 2; j++) acc[p][i][j] = (floatx4)0.f;

  for (int k0 = 0; k0 < H_; k0 += 32) {
    if (k0) __syncthreads();
    gld16(asd0, ap0 + k0);
    gld16(asd1, ap1 + k0);
    gld16(bsd0, bp0 + k0);
    gld16(bsd1, bp1 + k0);
    __syncthreads();
    bf16x8 a[4], bq[2][2];
    #pragma unroll
    for (int i = 0; i < 4; i++)
      a[i] = *(const bf16x8*)(As + (wr * 64 + i * 16 + half) * 32 + quad * 8);
    #pragma unroll
    for (int p = 0; p < 2; p++)
      #pragma unroll
      for (int j = 0; j < 2; j++)
        bq[p][j] = *(const bf16x8*)(Bs[p] + (wc * 32 + j * 16 + half) * 32 + quad * 8);
    #pragma unroll
    for (int i = 0; i < 4; i++)
      #pragma unroll
      for (int p = 0; p < 2; p++)
        #pragma unroll
        for (int j = 0; j < 2; j++)
          acc[p][i][j] = __builtin_amdgcn_mfma_f32_16x16x32_bf16(a[i], bq[p][j], acc[p][i][j], 0, 0, 0);
  }

  #pragma unroll
  for (int i = 0; i < 4; i++) {
    #pragma unroll
    for (int r = 0; r < 4; r++) {
      int g = row0 + wr * 64 + i * 16 + quad * 4 + r;
      if (g < cnt) {
        float w = EXPERT ? wlist[off + g] : 1.f;
        #pragma unroll
        for (int j = 0; j < 2; j++) {
          float va = acc[0][i][j][r];   // first-half col (proj / s_in)
          float vb = acc[1][i][j][r];   // second-half col (gate)
          float z  = EXPERT ? vb : va;  // expert: silu(gate); shared: silu(s_in)
          float o  = EXPERT ? va : vb;
          float sg = z / (1.f + expf(-z));
          float v  = sg * o * w;
          int col  = n0 + wc * 32 + j * 16 + half;
          act[(long)(off + g) * I_ + col] = f2bf(v);
        }
      }
    }
  }
}

// ---------------- GEMM2: out(+)= act @ B^T  (fp32 output) ----------------
// A: act rows (lda=I) bf16. B: (H,I) bf16 row-major. Block tile 128x128.
template<bool EXPERT>
__global__ __launch_bounds__(256, 2)
void gemm_out_k(const u16* __restrict__ A, const u16* __restrict__ Bbase, long Bstride,
                float* __restrict__ out, const int* __restrict__ list,
                const int* __restrict__ counts, const int* __restrict__ offsets) {
  __shared__ __align__(16) u16 As[128 * 32];
  __shared__ __align__(16) u16 Bs[128 * 32];

  int tid  = threadIdx.x;
  int lane = tid & 63, wv = tid >> 6;
  int wr   = wv >> 1, wc = wv & 1;
  int half = lane & 15, quad = lane >> 4;

  int cnt, off;
  const u16* B = Bbase;
  if (EXPERT) {
    int e = blockIdx.z;
    cnt = counts[e]; off = offsets[e];
    B += (long)e * Bstride;
  } else { cnt = T_; off = 0; }
  int row0 = blockIdx.y * 128;
  if (row0 >= cnt) return;
  int n0 = blockIdx.x * 128;

  int kc  = (tid & 3) * 8;
  int jl0 = row0 + (tid >> 2);
  int jl1 = jl0 + 64;
  long ar0 = off + min(jl0, cnt - 1);
  long ar1 = off + min(jl1, cnt - 1);
  const u16* ap0 = A + ar0 * I_ + kc;
  const u16* ap1 = A + ar1 * I_ + kc;
  int nl0 = n0 + (tid >> 2);
  const u16* bp0 = B + (long)nl0 * I_ + kc;
  const u16* bp1 = B + (long)(nl0 + 64) * I_ + kc;
  u16* asd0 = As + tid * 8;
  u16* asd1 = As + (tid + 256) * 8;
  u16* bsd0 = Bs + tid * 8;
  u16* bsd1 = Bs + (tid + 256) * 8;

  floatx4 acc[4][4];
  #pragma unroll
  for (int i = 0; i < 4; i++)
    #pragma unroll
    for (int j = 0; j < 4; j++) acc[i][j] = (floatx4)0.f;

  for (int k0 = 0; k0 < I_; k0 += 32) {
    if (k0) __syncthreads();
    gld16(asd0, ap0 + k0);
    gld16(asd1, ap1 + k0);
    gld16(bsd0, bp0 + k0);
    gld16(bsd1, bp1 + k0);
    __syncthreads();
    bf16x8 a[4], b[4];
    #pragma unroll
    for (int i = 0; i < 4; i++)
      a[i] = *(const bf16x8*)(As + (wr * 64 + i * 16 + half) * 32 + quad * 8);
    #pragma unroll
    for (int j = 0; j < 4; j++)
      b[j] = *(const bf16x8*)(Bs + (wc * 64 + j * 16 + half) * 32 + quad * 8);
    #pragma unroll
    for (int i = 0; i < 4; i++)
      #pragma unroll
      for (int j = 0; j < 4; j++)
        acc[i][j] = __builtin_amdgcn_mfma_f32_16x16x32_bf16(a[i], b[j], acc[i][j], 0, 0, 0);
  }

  #pragma unroll
  for (int i = 0; i < 4; i++) {
    #pragma unroll
    for (int r = 0; r < 4; r++) {
      int g = row0 + wr * 64 + i * 16 + quad * 4 + r;
      if (g < cnt) {
        int t = EXPERT ? list[off + g] : g;
        float* orow = out + (long)t * H_;
        #pragma unroll
        for (int j = 0; j < 4; j++) {
          int col = n0 + wc * 64 + j * 16 + half;
          float v = acc[i][j][r];
          if (EXPERT) atomicAdd(orow + col, v);
          else        orow[col] = v;
        }
      }
    }
  }
}

extern "C" void kernel_launch(void* const* d_in, const int* in_sizes, int n_in,
                              void* d_out, int out_size, void* d_ws, size_t ws_size,
                              hipStream_t stream) {
  const float* x      = (const float*)d_in[0];
  const float* gate_w = (const float*)d_in[1];
  const float* bias   = (const float*)d_in[2];
  const float* Wi     = (const float*)d_in[3];
  const float* Wo     = (const float*)d_in[4];
  const float* sWi    = (const float*)d_in[5];
  const float* sWo    = (const float*)d_in[6];
  float* out          = (float*)d_out;

  char* ws = (char*)d_ws;
  size_t o = 0;
  auto alloc = [&](size_t bytes) -> void* {
    o = (o + 255) & ~(size_t)255;
    void* p = ws + o;
    o += bytes;
    return p;
  };
  u16*   xb    = (u16*)  alloc((size_t)T_ * H_ * 2);
  u16*   sWib  = (u16*)  alloc((size_t)F2_ * H_ * 2);
  u16*   sWob  = (u16*)  alloc((size_t)H_ * I_ * 2);
  u16*   WiT   = (u16*)  alloc((size_t)E_ * F2_ * H_ * 2);
  u16*   WoT   = (u16*)  alloc((size_t)E_ * H_ * I_ * 2);
  u16*   shact = (u16*)  alloc((size_t)T_ * I_ * 2);
  u16*   ebuf  = (u16*)  alloc((size_t)2 * T_ * I_ * 2);
  int*   top2e = (int*)  alloc((size_t)T_ * 2 * 4);
  float* top2w = (float*)alloc((size_t)T_ * 2 * 4);
  int*   count = (int*)  alloc(E_ * 4);
  int*   offs  = (int*)  alloc(E_ * 4);
  int*   list  = (int*)  alloc((size_t)2 * T_ * 4);
  float* wlist = (float*)alloc((size_t)2 * T_ * 4);

  // routing (fp32), atomic-free; gate also converts x -> bf16
  gate_kernel<<<T_ / 4, 256, 0, stream>>>(x, gate_w, bias, top2e, top2w, xb);
  build_lists<<<1, 512, 0, stream>>>(top2e, top2w, count, offs, list, wlist);

  // fp32 -> bf16 conversions (weights)
  convert_f2b<<<(F2_ * H_) / 1024, 256, 0, stream>>>(sWi, sWib);
  convert_f2b<<<(H_ * I_) / 1024, 256, 0, stream>>>(sWo, sWob);
  // weight transposes (+convert) into B^T-friendly layout
  transpose_f2b<<<dim3(F2_ / 64, H_ / 64, E_), dim3(64, 8), 0, stream>>>(Wi, WiT, H_, F2_);
  transpose_f2b<<<dim3(H_ / 64, I_ / 64, E_), dim3(64, 8), 0, stream>>>(Wo, WoT, I_, H_);

  // shared branch (writes every element of out with plain stores)
  gemm_act<false><<<dim3(I_ / 64, T_ / 128, 1), 256, 0, stream>>>(
      xb, sWib, 0, shact, nullptr, nullptr, nullptr, nullptr);
  gemm_out_k<false><<<dim3(H_ / 128, T_ / 128, 1), 256, 0, stream>>>(
      shact, sWob, 0, out, nullptr, nullptr, nullptr);

  // expert branch (sparse, gathered; atomicAdd into out)
  gemm_act<true><<<dim3(I_ / 64, T_ / 128, E_), 256, 0, stream>>>(
      xb, WiT, (long)F2_ * H_, ebuf, list, wlist, count, offs);
  gemm_out_k<true><<<dim3(H_ / 128, T_ / 128, E_), 256, 0, stream>>>(
      ebuf, WoT, (long)H_ * I_, out, list, count, offs);
}

// Round 4
// 342.201 us; speedup vs baseline: 1.3509x; 1.1134x over previous
//
#include <hip/hip_runtime.h>
#include <stdint.h>

#define E_  8
#define H_  768
#define I_  1152
#define T_  4096
#define F2_ (2*I_)   // 2304

typedef unsigned short u16;
typedef __attribute__((ext_vector_type(8))) __bf16 bf16x8;
typedef __attribute__((ext_vector_type(4))) float floatx4;

typedef const void __attribute__((address_space(1))) as1_void;
typedef void __attribute__((address_space(3))) as3_void;

__device__ __forceinline__ void gld16(void* lds, const void* g) {
  __builtin_amdgcn_global_load_lds((as1_void*)g, (as3_void*)lds, 16, 0, 0);
}

__device__ __forceinline__ u16 f2bf(float f) {
  union { float f; unsigned int i; } v; v.f = f;
  unsigned int r = v.i + 0x7FFF + ((v.i >> 16) & 1);  // round-to-nearest-even
  return (u16)(r >> 16);
}

// ---------------- fp32 -> bf16 convert, two tensors in one launch ----------------
__global__ void convert_two(const float* __restrict__ s1, u16* __restrict__ d1, int n1,
                            const float* __restrict__ s2, u16* __restrict__ d2) {
  int i = (blockIdx.x * 256 + threadIdx.x) * 4;
  const float* s; u16* d;
  if (i < n1) { s = s1 + i; d = d1 + i; }
  else        { s = s2 + (i - n1); d = d2 + (i - n1); }
  float4 v = *(const float4*)s;
  ushort4 u;
  u.x = f2bf(v.x); u.y = f2bf(v.y); u.z = f2bf(v.z); u.w = f2bf(v.w);
  *(ushort4*)d = u;
}

// ------------- transpose + convert: src fp32 (R x C) -> dst bf16 (C x R), per z ----------
__global__ void transpose_f2b(const float* __restrict__ src, u16* __restrict__ dst,
                              int R, int C) {
  __shared__ u16 tile[64][65];
  const float* s = src + (long)blockIdx.z * R * C;
  u16*         d = dst + (long)blockIdx.z * R * C;
  int r0 = blockIdx.y * 64, c0 = blockIdx.x * 64;
  int tx = threadIdx.x, ty = threadIdx.y;   // (64, 8)
  #pragma unroll
  for (int k = 0; k < 64; k += 8)
    tile[ty + k][tx] = f2bf(s[(long)(r0 + ty + k) * C + (c0 + tx)]);
  __syncthreads();
  #pragma unroll
  for (int k = 0; k < 64; k += 8)
    d[(long)(c0 + ty + k) * R + (r0 + tx)] = tile[tx][ty + k];
}

// ---------------- gating: one wave per token (fp32 inputs), NO atomics ----------------
// Also fuses x fp32->bf16 conversion (each x element is read exactly once here).
__global__ void gate_kernel(const float* __restrict__ x, const float* __restrict__ gw,
                            const float* __restrict__ bias,
                            int* __restrict__ top2e, float* __restrict__ top2w,
                            u16* __restrict__ xb) {
  int t    = blockIdx.x * 4 + (threadIdx.x >> 6);
  int lane = threadIdx.x & 63;
  float acc[E_];
  #pragma unroll
  for (int e = 0; e < E_; e++) acc[e] = 0.f;
  #pragma unroll
  for (int k = lane; k < H_; k += 64) {
    float xv = x[(long)t * H_ + k];
    xb[(long)t * H_ + k] = f2bf(xv);
    #pragma unroll
    for (int e = 0; e < E_; e++) acc[e] += xv * gw[e * H_ + k];
  }
  #pragma unroll
  for (int e = 0; e < E_; e++) {
    #pragma unroll
    for (int s = 32; s > 0; s >>= 1) acc[e] += __shfl_xor(acc[e], s);
  }
  if (lane == 0) {
    float logits[E_], sel[E_];
    #pragma unroll
    for (int e = 0; e < E_; e++) {
      logits[e] = 1.f / (1.f + expf(-acc[e]));
      sel[e]    = logits[e] + bias[e];
    }
    int i0 = 0;
    #pragma unroll
    for (int e = 1; e < E_; e++) if (sel[e] > sel[i0]) i0 = e;
    int i1 = (i0 == 0) ? 1 : 0;
    #pragma unroll
    for (int e = 0; e < E_; e++) if (e != i0 && sel[e] > sel[i1]) i1 = e;
    float w0 = logits[i0], w1 = logits[i1], s = w0 + w1;
    top2e[t * 2 + 0] = i0;  top2w[t * 2 + 0] = w0 / s;
    top2e[t * 2 + 1] = i1;  top2w[t * 2 + 1] = w1 / s;
  }
}

// ---------------- build per-expert token lists: single block, zero atomics ----------------
// Wave e owns expert e. Also fills the shared branch's identity list (entries
// [2T, 3T)) and the inverse map pos[] used by final_reduce. counts/offs have 9
// entries: slot 8 = shared (cnt=T, off=2T).
__global__ void build_lists(const int* __restrict__ top2e, const float* __restrict__ top2w,
                            int* __restrict__ counts, int* __restrict__ offs,
                            int* __restrict__ list, float* __restrict__ wlist,
                            int* __restrict__ pos) {
  __shared__ int lds_cnt[E_];
  __shared__ int lds_off[E_];
  int wv = threadIdx.x >> 6, lane = threadIdx.x & 63;   // 512 threads = 8 waves

  int c = 0;
  for (int s = lane; s < 2 * T_; s += 64)
    if (top2e[s] == wv) c++;
  #pragma unroll
  for (int s = 32; s > 0; s >>= 1) c += __shfl_xor(c, s);
  if (lane == 0) lds_cnt[wv] = c;
  __syncthreads();
  if (threadIdx.x == 0) {
    int s = 0;
    #pragma unroll
    for (int e = 0; e < E_; e++) {
      lds_off[e] = s;
      counts[e]  = lds_cnt[e];
      offs[e]    = s;
      s += lds_cnt[e];
    }
    counts[8] = T_;
    offs[8]   = 2 * T_;
  }
  __syncthreads();

  int base = lds_off[wv];
  unsigned long long lt = (lane == 63) ? ~0ull >> 1 : ((1ull << lane) - 1);
  for (int s0 = 0; s0 < 2 * T_; s0 += 64) {
    int s = s0 + lane;
    bool m = (top2e[s] == wv);
    unsigned long long mask = __ballot(m);
    if (m) {
      int p = base + __popcll(mask & lt);
      list[p]  = s >> 1;        // token index
      wlist[p] = top2w[s];
      pos[s]   = p;
    }
    base += __popcll(mask);
  }
  // identity list for the shared branch (slot 8)
  for (int t = threadIdx.x; t < T_; t += 512) {
    list[2 * T_ + t]  = t;
    wlist[2 * T_ + t] = 1.f;
  }
}

// ---------------- GEMM1 (+fused SiLU): act = f(A_gathered @ B^T), 9 slots ----------------
// 1D grid, id = y*PP1 + pair, pair = z*18 + xblk. PP1 multiple of 8 so all
// row-blocks of one (z,xblk) weight slice share id%8 -> same XCD -> L2 reuse.
#define PP1 168   // pairs = 9*18 = 162, padded to multiple of 8
__global__ __launch_bounds__(256, 2)
void gemm_act_all(const u16* __restrict__ A, const u16* __restrict__ WiT,
                  const u16* __restrict__ sWib, u16* __restrict__ act,
                  const int* __restrict__ list, const float* __restrict__ wlist,
                  const int* __restrict__ counts, const int* __restrict__ offsets) {
  __shared__ __align__(16) u16 As[128 * 32];
  __shared__ __align__(16) u16 Bs[2][64 * 32];

  int id = blockIdx.x;
  int y  = id / PP1, p = id - y * PP1;
  if (p >= 162) return;
  int z = p / 18, xblk = p - z * 18;

  int cnt = counts[z], off = offsets[z];
  int row0 = y * 128;
  if (row0 >= cnt) return;
  const u16* B = (z == 8) ? sWib : (WiT + (long)z * F2_ * H_);
  int n0 = xblk * 64;

  int tid  = threadIdx.x;
  int lane = tid & 63, wv = tid >> 6;
  int wr   = wv >> 1, wc = wv & 1;
  int half = lane & 15, quad = lane >> 4;

  int kc  = (tid & 3) * 8;
  int jl0 = row0 + (tid >> 2);
  int jl1 = jl0 + 64;
  int rr0 = min(jl0, cnt - 1), rr1 = min(jl1, cnt - 1);
  int t0  = list[off + rr0];
  int t1  = list[off + rr1];
  const u16* ap0 = A + (long)t0 * H_ + kc;
  const u16* ap1 = A + (long)t1 * H_ + kc;
  int nloc = tid >> 2;
  const u16* bp0 = B + (long)(n0 + nloc) * H_ + kc;
  const u16* bp1 = B + (long)(I_ + n0 + nloc) * H_ + kc;
  u16* asd0 = As + tid * 8;
  u16* asd1 = As + (tid + 256) * 8;
  u16* bsd0 = Bs[0] + tid * 8;
  u16* bsd1 = Bs[1] + tid * 8;

  floatx4 acc[2][4][2];
  #pragma unroll
  for (int q = 0; q < 2; q++)
    #pragma unroll
    for (int i = 0; i < 4; i++)
      #pragma unroll
      for (int j = 0; j < 2; j++) acc[q][i][j] = (floatx4)0.f;

  for (int k0 = 0; k0 < H_; k0 += 32) {
    if (k0) __syncthreads();
    gld16(asd0, ap0 + k0);
    gld16(asd1, ap1 + k0);
    gld16(bsd0, bp0 + k0);
    gld16(bsd1, bp1 + k0);
    __syncthreads();
    bf16x8 a[4], bq[2][2];
    #pragma unroll
    for (int i = 0; i < 4; i++)
      a[i] = *(const bf16x8*)(As + (wr * 64 + i * 16 + half) * 32 + quad * 8);
    #pragma unroll
    for (int q = 0; q < 2; q++)
      #pragma unroll
      for (int j = 0; j < 2; j++)
        bq[q][j] = *(const bf16x8*)(Bs[q] + (wc * 32 + j * 16 + half) * 32 + quad * 8);
    #pragma unroll
    for (int i = 0; i < 4; i++)
      #pragma unroll
      for (int q = 0; q < 2; q++)
        #pragma unroll
        for (int j = 0; j < 2; j++)
          acc[q][i][j] = __builtin_amdgcn_mfma_f32_16x16x32_bf16(a[i], bq[q][j], acc[q][i][j], 0, 0, 0);
  }

  bool sh = (z == 8);
  #pragma unroll
  for (int i = 0; i < 4; i++) {
    #pragma unroll
    for (int r = 0; r < 4; r++) {
      int g = row0 + wr * 64 + i * 16 + quad * 4 + r;
      if (g < cnt) {
        float w = wlist[off + g];
        #pragma unroll
        for (int j = 0; j < 2; j++) {
          float va = acc[0][i][j][r];     // first-half col (proj / s_in)
          float vb = acc[1][i][j][r];     // second-half col (gate)
          float zz = sh ? va : vb;        // shared: silu(s_in); expert: silu(gate)
          float o  = sh ? vb : va;
          float sg = zz / (1.f + expf(-zz));
          float v  = sg * o * w;
          int col  = n0 + wc * 32 + j * 16 + half;
          act[(long)(off + g) * I_ + col] = f2bf(v);
        }
      }
    }
  }
}

// ---------------- GEMM2: rows of act @ B^T, plain stores (no atomics) ----------------
// z<8 -> eobuf slot rows; z==8 -> out token rows. Same XCD-grouping swizzle.
#define PP2 56    // pairs = 9*6 = 54, padded to multiple of 8
__global__ __launch_bounds__(256, 2)
void gemm_out_all(const u16* __restrict__ A, const u16* __restrict__ WoT,
                  const u16* __restrict__ sWob, float* __restrict__ out,
                  float* __restrict__ eobuf,
                  const int* __restrict__ counts, const int* __restrict__ offsets) {
  __shared__ __align__(16) u16 As[128 * 32];
  __shared__ __align__(16) u16 Bs[128 * 32];

  int id = blockIdx.x;
  int y  = id / PP2, p = id - y * PP2;
  if (p >= 54) return;
  int z = p / 6, xblk = p - z * 6;

  int cnt = counts[z], off = offsets[z];
  int row0 = y * 128;
  if (row0 >= cnt) return;
  const u16* B = (z == 8) ? sWob : (WoT + (long)z * H_ * I_);
  int n0 = xblk * 128;

  int tid  = threadIdx.x;
  int lane = tid & 63, wv = tid >> 6;
  int wr   = wv >> 1, wc = wv & 1;
  int half = lane & 15, quad = lane >> 4;

  int kc  = (tid & 3) * 8;
  int jl0 = row0 + (tid >> 2);
  int jl1 = jl0 + 64;
  long ar0 = off + min(jl0, cnt - 1);
  long ar1 = off + min(jl1, cnt - 1);
  const u16* ap0 = A + ar0 * I_ + kc;
  const u16* ap1 = A + ar1 * I_ + kc;
  int nl0 = n0 + (tid >> 2);
  const u16* bp0 = B + (long)nl0 * I_ + kc;
  const u16* bp1 = B + (long)(nl0 + 64) * I_ + kc;
  u16* asd0 = As + tid * 8;
  u16* asd1 = As + (tid + 256) * 8;
  u16* bsd0 = Bs + tid * 8;
  u16* bsd1 = Bs + (tid + 256) * 8;

  floatx4 acc[4][4];
  #pragma unroll
  for (int i = 0; i < 4; i++)
    #pragma unroll
    for (int j = 0; j < 4; j++) acc[i][j] = (floatx4)0.f;

  for (int k0 = 0; k0 < I_; k0 += 32) {
    if (k0) __syncthreads();
    gld16(asd0, ap0 + k0);
    gld16(asd1, ap1 + k0);
    gld16(bsd0, bp0 + k0);
    gld16(bsd1, bp1 + k0);
    __syncthreads();
    bf16x8 a[4], b[4];
    #pragma unroll
    for (int i = 0; i < 4; i++)
      a[i] = *(const bf16x8*)(As + (wr * 64 + i * 16 + half) * 32 + quad * 8);
    #pragma unroll
    for (int j = 0; j < 4; j++)
      b[j] = *(const bf16x8*)(Bs + (wc * 64 + j * 16 + half) * 32 + quad * 8);
    #pragma unroll
    for (int i = 0; i < 4; i++)
      #pragma unroll
      for (int j = 0; j < 4; j++)
        acc[i][j] = __builtin_amdgcn_mfma_f32_16x16x32_bf16(a[i], b[j], acc[i][j], 0, 0, 0);
  }

  bool sh = (z == 8);
  #pragma unroll
  for (int i = 0; i < 4; i++) {
    #pragma unroll
    for (int r = 0; r < 4; r++) {
      int g = row0 + wr * 64 + i * 16 + quad * 4 + r;
      if (g < cnt) {
        float* orow = sh ? (out + (long)g * H_) : (eobuf + (long)(off + g) * H_);
        #pragma unroll
        for (int j = 0; j < 4; j++) {
          int col = n0 + wc * 64 + j * 16 + half;
          orow[col] = acc[i][j][r];
        }
      }
    }
  }
}

// ---------------- final: out[t] += eobuf[pos0[t]] + eobuf[pos1[t]] ----------------
__global__ void final_reduce(float* __restrict__ out, const float* __restrict__ eobuf,
                             const int* __restrict__ pos) {
  int gid = blockIdx.x * 256 + threadIdx.x;    // T * 192 threads, one float4 each
  int t = gid / (H_ / 4), c = (gid % (H_ / 4)) * 4;
  int p0 = pos[t * 2], p1 = pos[t * 2 + 1];
  float4 a = *(const float4*)(out   + (long)t  * H_ + c);
  float4 b = *(const float4*)(eobuf + (long)p0 * H_ + c);
  float4 d = *(const float4*)(eobuf + (long)p1 * H_ + c);
  a.x += b.x + d.x; a.y += b.y + d.y; a.z += b.z + d.z; a.w += b.w + d.w;
  *(float4*)(out + (long)t * H_ + c) = a;
}

extern "C" void kernel_launch(void* const* d_in, const int* in_sizes, int n_in,
                              void* d_out, int out_size, void* d_ws, size_t ws_size,
                              hipStream_t stream) {
  const float* x      = (const float*)d_in[0];
  const float* gate_w = (const float*)d_in[1];
  const float* bias   = (const float*)d_in[2];
  const float* Wi     = (const float*)d_in[3];
  const float* Wo     = (const float*)d_in[4];
  const float* sWi    = (const float*)d_in[5];
  const float* sWo    = (const float*)d_in[6];
  float* out          = (float*)d_out;

  char* ws = (char*)d_ws;
  size_t o = 0;
  auto alloc = [&](size_t bytes) -> void* {
    o = (o + 255) & ~(size_t)255;
    void* p = ws + o;
    o += bytes;
    return p;
  };
  u16*   xb    = (u16*)  alloc((size_t)T_ * H_ * 2);
  u16*   sWib  = (u16*)  alloc((size_t)F2_ * H_ * 2);
  u16*   sWob  = (u16*)  alloc((size_t)H_ * I_ * 2);
  u16*   WiT   = (u16*)  alloc((size_t)E_ * F2_ * H_ * 2);   // 28.3 MB
  u16*   WoT   = (u16*)  alloc((size_t)E_ * H_ * I_ * 2);
  u16*   act   = (u16*)  alloc((size_t)3 * T_ * I_ * 2);     // 12288 rows (8192 exp + 4096 sh)
  int*   top2e = (int*)  alloc((size_t)T_ * 2 * 4);
  float* top2w = (float*)alloc((size_t)T_ * 2 * 4);
  int*   count = (int*)  alloc(9 * 4);
  int*   offs  = (int*)  alloc(9 * 4);
  int*   list  = (int*)  alloc((size_t)3 * T_ * 4);
  float* wlist = (float*)alloc((size_t)3 * T_ * 4);
  int*   pos   = (int*)  alloc((size_t)2 * T_ * 4);
  // eobuf (8192*768*4 = 25.2 MB) aliases WiT (28.3 MB): WiT is dead after gemm_act_all.
  float* eobuf = (float*)WiT;

  // routing (fp32), atomic-free; gate also converts x -> bf16
  gate_kernel<<<T_ / 4, 256, 0, stream>>>(x, gate_w, bias, top2e, top2w, xb);
  build_lists<<<1, 512, 0, stream>>>(top2e, top2w, count, offs, list, wlist, pos);

  // shared-weight converts (one launch) + expert-weight transposes
  convert_two<<<(F2_ * H_ + H_ * I_) / 1024, 256, 0, stream>>>(
      sWi, sWib, F2_ * H_, sWo, sWob);
  transpose_f2b<<<dim3(F2_ / 64, H_ / 64, E_), dim3(64, 8), 0, stream>>>(Wi, WiT, H_, F2_);
  transpose_f2b<<<dim3(H_ / 64, I_ / 64, E_), dim3(64, 8), 0, stream>>>(Wo, WoT, I_, H_);

  // batched GEMM1 (+SiLU) over 9 slots, XCD-grouped swizzle
  gemm_act_all<<<32 * PP1, 256, 0, stream>>>(xb, WiT, sWib, act, list, wlist, count, offs);
  // batched GEMM2 over 9 slots, plain stores
  gemm_out_all<<<32 * PP2, 256, 0, stream>>>(act, WoT, sWob, out, eobuf, count, offs);
  // gather-reduce the two expert contributions per token
  final_reduce<<<(T_ * (H_ / 4)) / 256, 256, 0, stream>>>(out, eobuf, pos);
}

// Round 5
// 294.550 us; speedup vs baseline: 1.5695x; 1.1618x over previous
//
#include <hip/hip_runtime.h>
#include <stdint.h>

#define E_  8
#define H_  768
#define I_  1152
#define T_  4096
#define F2_ (2*I_)   // 2304

typedef unsigned short u16;
typedef __attribute__((ext_vector_type(8))) __bf16 bf16x8;
typedef __attribute__((ext_vector_type(4))) float floatx4;

typedef const void __attribute__((address_space(1))) as1_void;
typedef void __attribute__((address_space(3))) as3_void;

__device__ __forceinline__ void gld16(void* lds, const void* g) {
  __builtin_amdgcn_global_load_lds((as1_void*)g, (as3_void*)lds, 16, 0, 0);
}

__device__ __forceinline__ u16 f2bf(float f) {
  union { float f; unsigned int i; } v; v.f = f;
  unsigned int r = v.i + 0x7FFF + ((v.i >> 16) & 1);  // round-to-nearest-even
  return (u16)(r >> 16);
}

// ---------------- fp32 -> bf16 convert, two tensors in one launch ----------------
__global__ void convert_two(const float* __restrict__ s1, u16* __restrict__ d1, int n1,
                            const float* __restrict__ s2, u16* __restrict__ d2) {
  int i = (blockIdx.x * 256 + threadIdx.x) * 4;
  const float* s; u16* d;
  if (i < n1) { s = s1 + i; d = d1 + i; }
  else        { s = s2 + (i - n1); d = d2 + (i - n1); }
  float4 v = *(const float4*)s;
  ushort4 u;
  u.x = f2bf(v.x); u.y = f2bf(v.y); u.z = f2bf(v.z); u.w = f2bf(v.w);
  *(ushort4*)d = u;
}

// ------------- transpose + convert: src fp32 (R x C) -> dst bf16 (C x R), per z ----------
__global__ void transpose_f2b(const float* __restrict__ src, u16* __restrict__ dst,
                              int R, int C) {
  __shared__ u16 tile[64][65];
  const float* s = src + (long)blockIdx.z * R * C;
  u16*         d = dst + (long)blockIdx.z * R * C;
  int r0 = blockIdx.y * 64, c0 = blockIdx.x * 64;
  int tx = threadIdx.x, ty = threadIdx.y;   // (64, 8)
  #pragma unroll
  for (int k = 0; k < 64; k += 8)
    tile[ty + k][tx] = f2bf(s[(long)(r0 + ty + k) * C + (c0 + tx)]);
  __syncthreads();
  #pragma unroll
  for (int k = 0; k < 64; k += 8)
    d[(long)(c0 + ty + k) * R + (r0 + tx)] = tile[tx][ty + k];
}

// ---------------- gating: one wave per token, float4 loads, NO atomics ----------------
__global__ void gate_kernel(const float* __restrict__ x, const float* __restrict__ gw,
                            const float* __restrict__ bias,
                            int* __restrict__ top2e, float* __restrict__ top2w,
                            u16* __restrict__ xb) {
  int t    = blockIdx.x * 4 + (threadIdx.x >> 6);
  int lane = threadIdx.x & 63;
  float acc[E_];
  #pragma unroll
  for (int e = 0; e < E_; e++) acc[e] = 0.f;
  #pragma unroll
  for (int i = 0; i < H_ / 256; i++) {        // 3 iterations, 4 floats each
    int c = i * 256 + lane * 4;
    float4 xv = *(const float4*)(x + (long)t * H_ + c);
    ushort4 u;
    u.x = f2bf(xv.x); u.y = f2bf(xv.y); u.z = f2bf(xv.z); u.w = f2bf(xv.w);
    *(ushort4*)(xb + (long)t * H_ + c) = u;
    #pragma unroll
    for (int e = 0; e < E_; e++) {
      float4 g = *(const float4*)(gw + e * H_ + c);
      acc[e] += xv.x * g.x + xv.y * g.y + xv.z * g.z + xv.w * g.w;
    }
  }
  #pragma unroll
  for (int e = 0; e < E_; e++) {
    #pragma unroll
    for (int s = 32; s > 0; s >>= 1) acc[e] += __shfl_xor(acc[e], s);
  }
  if (lane == 0) {
    float logits[E_], sel[E_];
    #pragma unroll
    for (int e = 0; e < E_; e++) {
      logits[e] = 1.f / (1.f + expf(-acc[e]));
      sel[e]    = logits[e] + bias[e];
    }
    int i0 = 0;
    #pragma unroll
    for (int e = 1; e < E_; e++) if (sel[e] > sel[i0]) i0 = e;
    int i1 = (i0 == 0) ? 1 : 0;
    #pragma unroll
    for (int e = 0; e < E_; e++) if (e != i0 && sel[e] > sel[i1]) i1 = e;
    float w0 = logits[i0], w1 = logits[i1], s = w0 + w1;
    top2e[t * 2 + 0] = i0;  top2w[t * 2 + 0] = w0 / s;
    top2e[t * 2 + 1] = i1;  top2w[t * 2 + 1] = w1 / s;
  }
}

// ---------------- build lists: 8 blocks (one per expert), zero atomics ----------------
__global__ void build_lists(const int* __restrict__ top2e, const float* __restrict__ top2w,
                            int* __restrict__ counts, int* __restrict__ offs,
                            int* __restrict__ list, float* __restrict__ wlist,
                            int* __restrict__ pos) {
  __shared__ int scnt[4][E_];
  __shared__ int sq[4];
  __shared__ int soffs[E_];
  int e = blockIdx.x;
  int tid = threadIdx.x, w = tid >> 6, lane = tid & 63;
  const int Q = (2 * T_) / 4;   // 2048 per wave-quarter

  int c8[E_];
  #pragma unroll
  for (int q = 0; q < E_; q++) c8[q] = 0;
  for (int i = tid; i < 2 * T_; i += 256) {
    int v = top2e[i];
    #pragma unroll
    for (int q = 0; q < E_; q++) c8[q] += (v == q);
  }
  int qstart = w * Q;
  int ce = 0;
  for (int i = qstart + lane; i < qstart + Q; i += 64) ce += (top2e[i] == e);
  #pragma unroll
  for (int q = 0; q < E_; q++)
    #pragma unroll
    for (int s = 32; s > 0; s >>= 1) c8[q] += __shfl_xor(c8[q], s);
  #pragma unroll
  for (int s = 32; s > 0; s >>= 1) ce += __shfl_xor(ce, s);
  if (lane == 0) {
    #pragma unroll
    for (int q = 0; q < E_; q++) scnt[w][q] = c8[q];
    sq[w] = ce;
  }
  __syncthreads();
  if (tid == 0) {
    int s = 0;
    #pragma unroll
    for (int q = 0; q < E_; q++) {
      int tot = scnt[0][q] + scnt[1][q] + scnt[2][q] + scnt[3][q];
      soffs[q] = s;
      if (e == 0) { counts[q] = tot; offs[q] = s; }
      s += tot;
    }
    if (e == 0) { counts[8] = T_; offs[8] = 2 * T_; }
  }
  __syncthreads();
  int base = soffs[e];
  #pragma unroll
  for (int w2 = 0; w2 < 4; w2++) if (w2 < w) base += sq[w2];
  unsigned long long lt = (lane == 63) ? (~0ull >> 1) : ((1ull << lane) - 1);
  for (int i0 = qstart; i0 < qstart + Q; i0 += 64) {
    int s = i0 + lane;
    bool m = (top2e[s] == e);
    unsigned long long mask = __ballot(m);
    if (m) {
      int p = base + __popcll(mask & lt);
      list[p]  = s >> 1;
      wlist[p] = top2w[s];
      pos[s]   = p;
    }
    base += __popcll(mask);
  }
  // identity list for shared slot, spread across the 8 blocks
  for (int t = e * (T_ / 8) + tid; t < (e + 1) * (T_ / 8); t += 256) {
    list[2 * T_ + t]  = t;
    wlist[2 * T_ + t] = 1.f;
  }
}

// ---------------- GEMM1 (+fused SiLU): act = f(A_gathered @ B^T), 9 slots ----------------
// BK=64, XOR-swizzled LDS (phys chunk = logical chunk ^ (row&7)) -> conflict-free b128.
#define PP1 168   // pairs = 9*18 = 162, padded to multiple of 8
__global__ __launch_bounds__(256, 2)
void gemm_act_all(const u16* __restrict__ A, const u16* __restrict__ WiT,
                  const u16* __restrict__ sWib, u16* __restrict__ act,
                  const int* __restrict__ list, const float* __restrict__ wlist,
                  const int* __restrict__ counts, const int* __restrict__ offsets) {
  __shared__ __align__(16) u16 As[128 * 64];
  __shared__ __align__(16) u16 Bs[2][64 * 64];

  int id = blockIdx.x;
  int y  = id / PP1, p = id - y * PP1;
  if (p >= 162) return;
  int z = p / 18, xblk = p - z * 18;

  int cnt = counts[z], off = offsets[z];
  int row0 = y * 128;
  if (row0 >= cnt) return;
  const u16* B = (z == 8) ? sWib : (WiT + (long)z * F2_ * H_);
  int n0 = xblk * 64;

  int tid  = threadIdx.x;
  int lane = tid & 63, wv = tid >> 6;
  int wr   = wv >> 1, wc = wv & 1;
  int half = lane & 15, quad = lane >> 4;

  // staging: lane covers rows rA + 32n, physical chunk tid&7, logical chunk swizzled
  int rA  = tid >> 3;                                // 0..31
  int lc8 = ((tid & 7) ^ (rA & 7)) * 8;              // k-offset within the 64-wide tile
  const u16* ap[4];
  #pragma unroll
  for (int n = 0; n < 4; n++) {
    int rr = min(row0 + rA + n * 32, cnt - 1);
    ap[n] = A + (long)list[off + rr] * H_ + lc8;
  }
  const u16* bp[2][2];
  #pragma unroll
  for (int h = 0; h < 2; h++)
    #pragma unroll
    for (int m = 0; m < 2; m++)
      bp[h][m] = B + (long)(h * I_ + n0 + m * 32 + rA) * H_ + lc8;

  floatx4 acc[2][4][2];
  #pragma unroll
  for (int q = 0; q < 2; q++)
    #pragma unroll
    for (int i = 0; i < 4; i++)
      #pragma unroll
      for (int j = 0; j < 2; j++) acc[q][i][j] = (floatx4)0.f;

  for (int k0 = 0; k0 < H_; k0 += 64) {
    if (k0) __syncthreads();
    #pragma unroll
    for (int n = 0; n < 4; n++) gld16(As + (n * 256 + tid) * 8, ap[n] + k0);
    #pragma unroll
    for (int h = 0; h < 2; h++)
      #pragma unroll
      for (int m = 0; m < 2; m++) gld16(Bs[h] + (m * 256 + tid) * 8, bp[h][m] + k0);
    __syncthreads();
    #pragma unroll
    for (int kk = 0; kk < 2; kk++) {
      int cs = ((kk * 4 + quad) ^ (half & 7)) * 8;   // swizzled chunk offset (u16)
      bf16x8 a[4], bq[2][2];
      #pragma unroll
      for (int i = 0; i < 4; i++)
        a[i] = *(const bf16x8*)(As + (wr * 64 + i * 16 + half) * 64 + cs);
      #pragma unroll
      for (int q = 0; q < 2; q++)
        #pragma unroll
        for (int j = 0; j < 2; j++)
          bq[q][j] = *(const bf16x8*)(Bs[q] + (wc * 32 + j * 16 + half) * 64 + cs);
      #pragma unroll
      for (int i = 0; i < 4; i++)
        #pragma unroll
        for (int q = 0; q < 2; q++)
          #pragma unroll
          for (int j = 0; j < 2; j++)
            acc[q][i][j] = __builtin_amdgcn_mfma_f32_16x16x32_bf16(a[i], bq[q][j], acc[q][i][j], 0, 0, 0);
    }
  }

  bool sh = (z == 8);
  #pragma unroll
  for (int i = 0; i < 4; i++) {
    #pragma unroll
    for (int r = 0; r < 4; r++) {
      int g = row0 + wr * 64 + i * 16 + quad * 4 + r;
      if (g < cnt) {
        float w = wlist[off + g];
        #pragma unroll
        for (int j = 0; j < 2; j++) {
          float va = acc[0][i][j][r];     // first-half col (proj / s_in)
          float vb = acc[1][i][j][r];     // second-half col (gate)
          float zz = sh ? va : vb;        // shared: silu(s_in); expert: silu(gate)
          float o  = sh ? vb : va;
          float sg = zz / (1.f + expf(-zz));
          float v  = sg * o * w;
          int col  = n0 + wc * 32 + j * 16 + half;
          act[(long)(off + g) * I_ + col] = f2bf(v);
        }
      }
    }
  }
}

// ---------------- GEMM2: rows of act @ B^T, plain stores (no atomics) ----------------
#define PP2 56    // pairs = 9*6 = 54, padded to multiple of 8
__global__ __launch_bounds__(256, 2)
void gemm_out_all(const u16* __restrict__ A, const u16* __restrict__ WoT,
                  const u16* __restrict__ sWob, float* __restrict__ out,
                  float* __restrict__ eobuf,
                  const int* __restrict__ counts, const int* __restrict__ offsets) {
  __shared__ __align__(16) u16 As[128 * 64];
  __shared__ __align__(16) u16 Bs[128 * 64];

  int id = blockIdx.x;
  int y  = id / PP2, p = id - y * PP2;
  if (p >= 54) return;
  int z = p / 6, xblk = p - z * 6;

  int cnt = counts[z], off = offsets[z];
  int row0 = y * 128;
  if (row0 >= cnt) return;
  const u16* B = (z == 8) ? sWob : (WoT + (long)z * H_ * I_);
  int n0 = xblk * 128;

  int tid  = threadIdx.x;
  int lane = tid & 63, wv = tid >> 6;
  int wr   = wv >> 1, wc = wv & 1;
  int half = lane & 15, quad = lane >> 4;

  int rA  = tid >> 3;
  int lc8 = ((tid & 7) ^ (rA & 7)) * 8;
  const u16* ap[4];
  #pragma unroll
  for (int n = 0; n < 4; n++) {
    long rr = off + min(row0 + rA + n * 32, cnt - 1);
    ap[n] = A + rr * I_ + lc8;
  }
  const u16* bp[4];
  #pragma unroll
  for (int m = 0; m < 4; m++)
    bp[m] = B + (long)(n0 + m * 32 + rA) * I_ + lc8;

  floatx4 acc[4][4];
  #pragma unroll
  for (int i = 0; i < 4; i++)
    #pragma unroll
    for (int j = 0; j < 4; j++) acc[i][j] = (floatx4)0.f;

  for (int k0 = 0; k0 < I_; k0 += 64) {
    if (k0) __syncthreads();
    #pragma unroll
    for (int n = 0; n < 4; n++) gld16(As + (n * 256 + tid) * 8, ap[n] + k0);
    #pragma unroll
    for (int m = 0; m < 4; m++) gld16(Bs + (m * 256 + tid) * 8, bp[m] + k0);
    __syncthreads();
    #pragma unroll
    for (int kk = 0; kk < 2; kk++) {
      int cs = ((kk * 4 + quad) ^ (half & 7)) * 8;
      bf16x8 a[4], b[4];
      #pragma unroll
      for (int i = 0; i < 4; i++)
        a[i] = *(const bf16x8*)(As + (wr * 64 + i * 16 + half) * 64 + cs);
      #pragma unroll
      for (int j = 0; j < 4; j++)
        b[j] = *(const bf16x8*)(Bs + (wc * 64 + j * 16 + half) * 64 + cs);
      #pragma unroll
      for (int i = 0; i < 4; i++)
        #pragma unroll
        for (int j = 0; j < 4; j++)
          acc[i][j] = __builtin_amdgcn_mfma_f32_16x16x32_bf16(a[i], b[j], acc[i][j], 0, 0, 0);
    }
  }

  bool sh = (z == 8);
  #pragma unroll
  for (int i = 0; i < 4; i++) {
    #pragma unroll
    for (int r = 0; r < 4; r++) {
      int g = row0 + wr * 64 + i * 16 + quad * 4 + r;
      if (g < cnt) {
        float* orow = sh ? (out + (long)g * H_) : (eobuf + (long)(off + g) * H_);
        #pragma unroll
        for (int j = 0; j < 4; j++) {
          int col = n0 + wc * 64 + j * 16 + half;
          orow[col] = acc[i][j][r];
        }
      }
    }
  }
}

// ---------------- final: out[t] += eobuf[pos0[t]] + eobuf[pos1[t]] ----------------
__global__ void final_reduce(float* __restrict__ out, const float* __restrict__ eobuf,
                             const int* __restrict__ pos) {
  int gid = blockIdx.x * 256 + threadIdx.x;
  int t = gid / (H_ / 4), c = (gid % (H_ / 4)) * 4;
  int p0 = pos[t * 2], p1 = pos[t * 2 + 1];
  float4 a = *(const float4*)(out   + (long)t  * H_ + c);
  float4 b = *(const float4*)(eobuf + (long)p0 * H_ + c);
  float4 d = *(const float4*)(eobuf + (long)p1 * H_ + c);
  a.x += b.x + d.x; a.y += b.y + d.y; a.z += b.z + d.z; a.w += b.w + d.w;
  *(float4*)(out + (long)t * H_ + c) = a;
}

extern "C" void kernel_launch(void* const* d_in, const int* in_sizes, int n_in,
                              void* d_out, int out_size, void* d_ws, size_t ws_size,
                              hipStream_t stream) {
  const float* x      = (const float*)d_in[0];
  const float* gate_w = (const float*)d_in[1];
  const float* bias   = (const float*)d_in[2];
  const float* Wi     = (const float*)d_in[3];
  const float* Wo     = (const float*)d_in[4];
  const float* sWi    = (const float*)d_in[5];
  const float* sWo    = (const float*)d_in[6];
  float* out          = (float*)d_out;

  char* ws = (char*)d_ws;
  size_t o = 0;
  auto alloc = [&](size_t bytes) -> void* {
    o = (o + 255) & ~(size_t)255;
    void* p = ws + o;
    o += bytes;
    return p;
  };
  u16*   xb    = (u16*)  alloc((size_t)T_ * H_ * 2);
  u16*   sWib  = (u16*)  alloc((size_t)F2_ * H_ * 2);
  u16*   sWob  = (u16*)  alloc((size_t)H_ * I_ * 2);
  u16*   WiT   = (u16*)  alloc((size_t)E_ * F2_ * H_ * 2);   // 28.3 MB
  u16*   WoT   = (u16*)  alloc((size_t)E_ * H_ * I_ * 2);
  u16*   act   = (u16*)  alloc((size_t)3 * T_ * I_ * 2);
  int*   top2e = (int*)  alloc((size_t)T_ * 2 * 4);
  float* top2w = (float*)alloc((size_t)T_ * 2 * 4);
  int*   count = (int*)  alloc(9 * 4);
  int*   offs  = (int*)  alloc(9 * 4);
  int*   list  = (int*)  alloc((size_t)3 * T_ * 4);
  float* wlist = (float*)alloc((size_t)3 * T_ * 4);
  int*   pos   = (int*)  alloc((size_t)2 * T_ * 4);
  // eobuf (8192*768*4 = 25.2 MB) aliases WiT (28.3 MB): WiT dead after gemm_act_all.
  float* eobuf = (float*)WiT;

  gate_kernel<<<T_ / 4, 256, 0, stream>>>(x, gate_w, bias, top2e, top2w, xb);
  build_lists<<<E_, 256, 0, stream>>>(top2e, top2w, count, offs, list, wlist, pos);

  convert_two<<<(F2_ * H_ + H_ * I_) / 1024, 256, 0, stream>>>(
      sWi, sWib, F2_ * H_, sWo, sWob);
  transpose_f2b<<<dim3(F2_ / 64, H_ / 64, E_), dim3(64, 8), 0, stream>>>(Wi, WiT, H_, F2_);
  transpose_f2b<<<dim3(H_ / 64, I_ / 64, E_), dim3(64, 8), 0, stream>>>(Wo, WoT, I_, H_);

  gemm_act_all<<<32 * PP1, 256, 0, stream>>>(xb, WiT, sWib, act, list, wlist, count, offs);
  gemm_out_all<<<32 * PP2, 256, 0, stream>>>(act, WoT, sWob, out, eobuf, count, offs);
  final_reduce<<<(T_ * (H_ / 4)) / 256, 256, 0, stream>>>(out, eobuf, pos);
}